// Round 1
// baseline (33.199 us; speedup 1.0000x reference)
//
#include <hip/hip_runtime.h>
#include <math.h>

// ForwardKinematics: B=65536 graphs x 24 joints, fixed tree (compile-time).
// One thread per graph. DFS order: 0,1,2,3,4 | 5,6,7,8 | 9,10,11,[s1] 12,[s2] 13,
// 22,23(from s2), 14,15,16,17(from s1), 18,19,20,21(from s1).

__device__ __forceinline__ void rot6d(float a0, float a1, float a2,
                                      float a3, float a4, float a5,
                                      float T[9]) {
    float n1 = sqrtf(a0*a0 + a1*a1 + a2*a2) + 1e-12f;
    float i1 = 1.0f / n1;
    float b1x = a0*i1, b1y = a1*i1, b1z = a2*i1;
    float d = b1x*a3 + b1y*a4 + b1z*a5;
    float ax = a3 - d*b1x, ay = a4 - d*b1y, az = a5 - d*b1z;
    float n2 = sqrtf(ax*ax + ay*ay + az*az) + 1e-12f;
    float i2 = 1.0f / n2;
    float b2x = ax*i2, b2y = ay*i2, b2z = az*i2;
    T[0] = b1x; T[1] = b1y; T[2] = b1z;
    T[3] = b2x; T[4] = b2y; T[5] = b2z;
    T[6] = b1y*b2z - b1z*b2y;
    T[7] = b1z*b2x - b1x*b2z;
    T[8] = b1x*b2y - b1y*b2x;
}

// One chain step: child joint J. R,Pc updated in place; P[J*3..] written.
template<int J>
__device__ __forceinline__ void step(const float* __restrict__ xb,
                                     const float* __restrict__ ob,
                                     float R[9], float Pc[3], float* P) {
    const float2* v = reinterpret_cast<const float2*>(xb + J*6); // 8B-aligned always
    float2 v0 = v[0], v1 = v[1], v2 = v[2];
    float T[9];
    rot6d(v0.x, v0.y, v1.x, v1.y, v2.x, v2.y, T);
    float o0 = ob[J*3+0], o1 = ob[J*3+1], o2 = ob[J*3+2];
    float p0 = R[0]*o0 + R[1]*o1 + R[2]*o2 + Pc[0];
    float p1 = R[3]*o0 + R[4]*o1 + R[5]*o2 + Pc[1];
    float p2 = R[6]*o0 + R[7]*o1 + R[8]*o2 + Pc[2];
    float Rn[9];
    for (int i = 0; i < 3; ++i)
        for (int k = 0; k < 3; ++k)
            Rn[i*3+k] = R[i*3+0]*T[0+k] + R[i*3+1]*T[3+k] + R[i*3+2]*T[6+k];
    for (int i = 0; i < 9; ++i) R[i] = Rn[i];
    Pc[0] = p0; Pc[1] = p1; Pc[2] = p2;
    P[J*3+0] = p0; P[J*3+1] = p1; P[J*3+2] = p2;
}

__global__ __launch_bounds__(256) void fk_kernel(const float* __restrict__ x,
                                                 const float* __restrict__ off,
                                                 float* __restrict__ out, int B) {
    int b = blockIdx.x * blockDim.x + threadIdx.x;
    if (b >= B) return;
    const float* xb = x   + (size_t)b * 144;
    const float* ob = off + (size_t)b * 72;

    float P[72];
    float R[9], Pc[3];
    float R0[9];
    float R11[9], P11[3];
    float R12[9], P12[3];

    // root (joint 0): pos = 0, rot = T0
    {
        const float2* v = reinterpret_cast<const float2*>(xb);
        float2 v0 = v[0], v1 = v[1], v2 = v[2];
        rot6d(v0.x, v0.y, v1.x, v1.y, v2.x, v2.y, R);
        Pc[0] = Pc[1] = Pc[2] = 0.0f;
        P[0] = 0.0f; P[1] = 0.0f; P[2] = 0.0f;
        for (int i = 0; i < 9; ++i) R0[i] = R[i];
    }

    // chain A: 0 -> 1 -> 2 -> 3 -> 4
    step<1>(xb, ob, R, Pc, P);
    step<2>(xb, ob, R, Pc, P);
    step<3>(xb, ob, R, Pc, P);
    step<4>(xb, ob, R, Pc, P);

    // chain B: 0 -> 5 -> 6 -> 7 -> 8
    for (int i = 0; i < 9; ++i) R[i] = R0[i];
    Pc[0] = Pc[1] = Pc[2] = 0.0f;
    step<5>(xb, ob, R, Pc, P);
    step<6>(xb, ob, R, Pc, P);
    step<7>(xb, ob, R, Pc, P);
    step<8>(xb, ob, R, Pc, P);

    // chain C: 0 -> 9 -> 10 -> 11
    for (int i = 0; i < 9; ++i) R[i] = R0[i];
    Pc[0] = Pc[1] = Pc[2] = 0.0f;
    step<9>(xb, ob, R, Pc, P);
    step<10>(xb, ob, R, Pc, P);
    step<11>(xb, ob, R, Pc, P);
    for (int i = 0; i < 9; ++i) R11[i] = R[i];
    P11[0] = Pc[0]; P11[1] = Pc[1]; P11[2] = Pc[2];

    // 11 -> 12
    step<12>(xb, ob, R, Pc, P);
    for (int i = 0; i < 9; ++i) R12[i] = R[i];
    P12[0] = Pc[0]; P12[1] = Pc[1]; P12[2] = Pc[2];

    // 12 -> 13
    step<13>(xb, ob, R, Pc, P);

    // 12 -> 22 -> 23
    for (int i = 0; i < 9; ++i) R[i] = R12[i];
    Pc[0] = P12[0]; Pc[1] = P12[1]; Pc[2] = P12[2];
    step<22>(xb, ob, R, Pc, P);
    step<23>(xb, ob, R, Pc, P);

    // 11 -> 14 -> 15 -> 16 -> 17
    for (int i = 0; i < 9; ++i) R[i] = R11[i];
    Pc[0] = P11[0]; Pc[1] = P11[1]; Pc[2] = P11[2];
    step<14>(xb, ob, R, Pc, P);
    step<15>(xb, ob, R, Pc, P);
    step<16>(xb, ob, R, Pc, P);
    step<17>(xb, ob, R, Pc, P);

    // 11 -> 18 -> 19 -> 20 -> 21
    for (int i = 0; i < 9; ++i) R[i] = R11[i];
    Pc[0] = P11[0]; Pc[1] = P11[1]; Pc[2] = P11[2];
    step<18>(xb, ob, R, Pc, P);
    step<19>(xb, ob, R, Pc, P);
    step<20>(xb, ob, R, Pc, P);
    step<21>(xb, ob, R, Pc, P);

    // write 72 floats = 18 x float4 (b*288 B is 16B-aligned)
    float4* o4 = reinterpret_cast<float4*>(out + (size_t)b * 72);
    for (int i = 0; i < 18; ++i)
        o4[i] = make_float4(P[i*4+0], P[i*4+1], P[i*4+2], P[i*4+3]);
}

extern "C" void kernel_launch(void* const* d_in, const int* in_sizes, int n_in,
                              void* d_out, int out_size, void* d_ws, size_t ws_size,
                              hipStream_t stream) {
    const float* x   = (const float*)d_in[0];
    const float* off = (const float*)d_in[2];
    float* out = (float*)d_out;
    int B = in_sizes[0] / 144;   // x is (B*24, 6)
    int block = 256;
    int grid = (B + block - 1) / block;
    fk_kernel<<<grid, block, 0, stream>>>(x, off, out, B);
}

// Round 2
// 22.077 us; speedup vs baseline: 1.5038x; 1.5038x over previous
//
#include <hip/hip_runtime.h>
#include <math.h>

// ForwardKinematics: B graphs x 24 joints, fixed tree (compile-time).
// Monotone DFS order: 0,1,2,3,4,5,6,7,8,9,10,11,12,13,14,15,16,17,18,19,20,21,22,23
// with resets: J5<-R0, J9<-R0, J14<-R11, J18<-R11, J22<-R12.
// Block = 128 threads = 128 graphs. x/offset streamed in 4 chunks of 6 joints,
// staged via registers into TRANSPOSED LDS [feature][graph] (row stride 129),
// so compute-phase reads (f*129 + t) are bank-conflict-free. Output staged
// transposed in LDS, then written fully coalesced as float4.

#define GPB 128
#define PAD 129

__device__ __forceinline__ void rot6d(float a0, float a1, float a2,
                                      float a3, float a4, float a5,
                                      float T[9]) {
    float n1 = sqrtf(a0*a0 + a1*a1 + a2*a2) + 1e-12f;
    float i1 = 1.0f / n1;
    float b1x = a0*i1, b1y = a1*i1, b1z = a2*i1;
    float d = b1x*a3 + b1y*a4 + b1z*a5;
    float ax = a3 - d*b1x, ay = a4 - d*b1y, az = a5 - d*b1z;
    float n2 = sqrtf(ax*ax + ay*ay + az*az) + 1e-12f;
    float i2 = 1.0f / n2;
    float b2x = ax*i2, b2y = ay*i2, b2z = az*i2;
    T[0] = b1x; T[1] = b1y; T[2] = b1z;
    T[3] = b2x; T[4] = b2y; T[5] = b2z;
    T[6] = b1y*b2z - b1z*b2y;
    T[7] = b1z*b2x - b1x*b2z;
    T[8] = b1x*b2y - b1y*b2x;
}

__device__ __forceinline__ void load_x(const float4* __restrict__ x4, long base4,
                                       int c, int t, float4 xr[9]) {
#pragma unroll
    for (int k = 0; k < 9; ++k) {
        int i = k * GPB + t;
        int g = i / 9, e = i - g * 9;
        xr[k] = x4[base4 + (long)g * 36 + c * 9 + e];
    }
}

__device__ __forceinline__ void load_o(const float2* __restrict__ o2, long base2,
                                       int c, int t, float2 orr[9]) {
#pragma unroll
    for (int k = 0; k < 9; ++k) {
        int i = k * GPB + t;
        int g = i / 9, e = i - g * 9;
        orr[k] = o2[base2 + (long)g * 36 + c * 9 + e];
    }
}

__device__ __forceinline__ void write_lds(float* xs, float* os_, int t,
                                          const float4 xr[9], const float2 orr[9]) {
#pragma unroll
    for (int k = 0; k < 9; ++k) {
        int i = k * GPB + t;
        int g = i / 9, e = i - g * 9;
        xs[(4*e+0)*PAD + g] = xr[k].x;
        xs[(4*e+1)*PAD + g] = xr[k].y;
        xs[(4*e+2)*PAD + g] = xr[k].z;
        xs[(4*e+3)*PAD + g] = xr[k].w;
        os_[(2*e+0)*PAD + g] = orr[k].x;
        os_[(2*e+1)*PAD + g] = orr[k].y;
    }
}

// One chain step: joint J (local jl = J%6 within the staged chunk).
template<int J>
__device__ __forceinline__ void joint_step(const float* xs, const float* os_,
                                           float* outs, int t,
                                           float R[9], float Pc[3]) {
    constexpr int jl = J % 6;
    float a0 = xs[(jl*6+0)*PAD + t];
    float a1 = xs[(jl*6+1)*PAD + t];
    float a2 = xs[(jl*6+2)*PAD + t];
    float a3 = xs[(jl*6+3)*PAD + t];
    float a4 = xs[(jl*6+4)*PAD + t];
    float a5 = xs[(jl*6+5)*PAD + t];
    float T[9];
    rot6d(a0, a1, a2, a3, a4, a5, T);
    float o0 = os_[(jl*3+0)*PAD + t];
    float o1 = os_[(jl*3+1)*PAD + t];
    float o2 = os_[(jl*3+2)*PAD + t];
    float p0 = R[0]*o0 + R[1]*o1 + R[2]*o2 + Pc[0];
    float p1 = R[3]*o0 + R[4]*o1 + R[5]*o2 + Pc[1];
    float p2 = R[6]*o0 + R[7]*o1 + R[8]*o2 + Pc[2];
    float Rn[9];
#pragma unroll
    for (int i = 0; i < 3; ++i)
#pragma unroll
        for (int k = 0; k < 3; ++k)
            Rn[i*3+k] = R[i*3+0]*T[0+k] + R[i*3+1]*T[3+k] + R[i*3+2]*T[6+k];
#pragma unroll
    for (int i = 0; i < 9; ++i) R[i] = Rn[i];
    Pc[0] = p0; Pc[1] = p1; Pc[2] = p2;
    outs[(J*3+0)*PAD + t] = p0;
    outs[(J*3+1)*PAD + t] = p1;
    outs[(J*3+2)*PAD + t] = p2;
}

__global__ __launch_bounds__(GPB) void fk_kernel(const float* __restrict__ x,
                                                 const float* __restrict__ off,
                                                 float* __restrict__ out, int B) {
    __shared__ float xs[36 * PAD];
    __shared__ float os_[18 * PAD];
    __shared__ float outs[72 * PAD];
    int t = threadIdx.x;
    long gb0 = (long)blockIdx.x * GPB;
    const float4* x4 = (const float4*)x;
    const float2* o2g = (const float2*)off;
    long xb4 = gb0 * 36;
    long ob2 = gb0 * 36;

    float4 xr[9]; float2 orr[9];
    float R[9], Pc[3], R0[9], R11[9], P11[3], R12[9], P12[3];

    // prologue: stage chunk 0
    load_x(x4, xb4, 0, t, xr);
    load_o(o2g, ob2, 0, t, orr);
    write_lds(xs, os_, t, xr, orr);
    __syncthreads();

    // ---- chunk 0: joints 0..5 ----
    load_x(x4, xb4, 1, t, xr);      // prefetch chunk 1 (hidden under compute)
    load_o(o2g, ob2, 1, t, orr);
    {   // J0 root: pos=0, R=T0
        float a0 = xs[0*PAD+t], a1 = xs[1*PAD+t], a2 = xs[2*PAD+t];
        float a3 = xs[3*PAD+t], a4 = xs[4*PAD+t], a5 = xs[5*PAD+t];
        rot6d(a0, a1, a2, a3, a4, a5, R);
        Pc[0] = Pc[1] = Pc[2] = 0.0f;
        outs[0*PAD+t] = 0.0f; outs[1*PAD+t] = 0.0f; outs[2*PAD+t] = 0.0f;
#pragma unroll
        for (int i = 0; i < 9; ++i) R0[i] = R[i];
    }
    joint_step<1>(xs, os_, outs, t, R, Pc);
    joint_step<2>(xs, os_, outs, t, R, Pc);
    joint_step<3>(xs, os_, outs, t, R, Pc);
    joint_step<4>(xs, os_, outs, t, R, Pc);
#pragma unroll
    for (int i = 0; i < 9; ++i) R[i] = R0[i];
    Pc[0] = Pc[1] = Pc[2] = 0.0f;
    joint_step<5>(xs, os_, outs, t, R, Pc);
    __syncthreads();
    write_lds(xs, os_, t, xr, orr);
    __syncthreads();

    // ---- chunk 1: joints 6..11 ----
    load_x(x4, xb4, 2, t, xr);
    load_o(o2g, ob2, 2, t, orr);
    joint_step<6>(xs, os_, outs, t, R, Pc);
    joint_step<7>(xs, os_, outs, t, R, Pc);
    joint_step<8>(xs, os_, outs, t, R, Pc);
#pragma unroll
    for (int i = 0; i < 9; ++i) R[i] = R0[i];
    Pc[0] = Pc[1] = Pc[2] = 0.0f;
    joint_step<9>(xs, os_, outs, t, R, Pc);
    joint_step<10>(xs, os_, outs, t, R, Pc);
    joint_step<11>(xs, os_, outs, t, R, Pc);
#pragma unroll
    for (int i = 0; i < 9; ++i) R11[i] = R[i];
    P11[0] = Pc[0]; P11[1] = Pc[1]; P11[2] = Pc[2];
    __syncthreads();
    write_lds(xs, os_, t, xr, orr);
    __syncthreads();

    // ---- chunk 2: joints 12..17 ----
    load_x(x4, xb4, 3, t, xr);
    load_o(o2g, ob2, 3, t, orr);
    joint_step<12>(xs, os_, outs, t, R, Pc);
#pragma unroll
    for (int i = 0; i < 9; ++i) R12[i] = R[i];
    P12[0] = Pc[0]; P12[1] = Pc[1]; P12[2] = Pc[2];
    joint_step<13>(xs, os_, outs, t, R, Pc);
#pragma unroll
    for (int i = 0; i < 9; ++i) R[i] = R11[i];
    Pc[0] = P11[0]; Pc[1] = P11[1]; Pc[2] = P11[2];
    joint_step<14>(xs, os_, outs, t, R, Pc);
    joint_step<15>(xs, os_, outs, t, R, Pc);
    joint_step<16>(xs, os_, outs, t, R, Pc);
    joint_step<17>(xs, os_, outs, t, R, Pc);
    __syncthreads();
    write_lds(xs, os_, t, xr, orr);
    __syncthreads();

    // ---- chunk 3: joints 18..23 ----
#pragma unroll
    for (int i = 0; i < 9; ++i) R[i] = R11[i];
    Pc[0] = P11[0]; Pc[1] = P11[1]; Pc[2] = P11[2];
    joint_step<18>(xs, os_, outs, t, R, Pc);
    joint_step<19>(xs, os_, outs, t, R, Pc);
    joint_step<20>(xs, os_, outs, t, R, Pc);
    joint_step<21>(xs, os_, outs, t, R, Pc);
#pragma unroll
    for (int i = 0; i < 9; ++i) R[i] = R12[i];
    Pc[0] = P12[0]; Pc[1] = P12[1]; Pc[2] = P12[2];
    joint_step<22>(xs, os_, outs, t, R, Pc);
    joint_step<23>(xs, os_, outs, t, R, Pc);
    __syncthreads();

    // ---- output phase: fully coalesced float4 stores ----
    float4* out4 = (float4*)out;
    long outb4 = gb0 * 18;
#pragma unroll
    for (int k = 0; k < 18; ++k) {
        int i = k * GPB + t;
        int g = i / 18, e = i - g * 18;
        float4 v;
        v.x = outs[(4*e+0)*PAD + g];
        v.y = outs[(4*e+1)*PAD + g];
        v.z = outs[(4*e+2)*PAD + g];
        v.w = outs[(4*e+3)*PAD + g];
        out4[outb4 + i] = v;
    }
}

// Fallback (per-thread, from R0) for B not divisible by GPB — not expected here.
__global__ __launch_bounds__(256) void fk_tail(const float* __restrict__ x,
                                               const float* __restrict__ off,
                                               float* __restrict__ out,
                                               int b0, int B) {
    int b = b0 + blockIdx.x * blockDim.x + threadIdx.x;
    if (b >= B) return;
    const float* xb = x + (size_t)b * 144;
    const float* ob = off + (size_t)b * 72;
    float* P = out + (size_t)b * 72;
    float R[9], Pc[3], R0[9], R11[9], P11[3], R12[9], P12[3];
    {
        rot6d(xb[0], xb[1], xb[2], xb[3], xb[4], xb[5], R);
        Pc[0] = Pc[1] = Pc[2] = 0.0f;
        P[0] = P[1] = P[2] = 0.0f;
        for (int i = 0; i < 9; ++i) R0[i] = R[i];
    }
    const int parent[24] = {-1,0,1,2,3,0,5,6,7,0,9,10,11,12,11,14,15,16,11,18,19,20,12,22};
    // sequential monotone order works for this tree
    for (int j = 1; j < 24; ++j) {
        int p = parent[j];
        float Rp[9], Pp[3];
        if (p == 0)       { for (int i=0;i<9;++i) Rp[i]=R0[i];  Pp[0]=Pp[1]=Pp[2]=0.f; }
        else if (j==14||j==18) { for (int i=0;i<9;++i) Rp[i]=R11[i]; Pp[0]=P11[0];Pp[1]=P11[1];Pp[2]=P11[2]; }
        else if (j==22)   { for (int i=0;i<9;++i) Rp[i]=R12[i]; Pp[0]=P12[0];Pp[1]=P12[1];Pp[2]=P12[2]; }
        else              { for (int i=0;i<9;++i) Rp[i]=R[i];   Pp[0]=Pc[0];Pp[1]=Pc[1];Pp[2]=Pc[2]; }
        float T[9];
        rot6d(xb[j*6+0],xb[j*6+1],xb[j*6+2],xb[j*6+3],xb[j*6+4],xb[j*6+5],T);
        float o0=ob[j*3+0],o1=ob[j*3+1],o2=ob[j*3+2];
        Pc[0]=Rp[0]*o0+Rp[1]*o1+Rp[2]*o2+Pp[0];
        Pc[1]=Rp[3]*o0+Rp[4]*o1+Rp[5]*o2+Pp[1];
        Pc[2]=Rp[6]*o0+Rp[7]*o1+Rp[8]*o2+Pp[2];
        for (int i=0;i<3;++i) for (int k=0;k<3;++k) {
            float s=0.f; for (int m=0;m<3;++m) s+=Rp[i*3+m]*T[m*3+k];
            R[i*3+k]=s;
        }
        P[j*3+0]=Pc[0]; P[j*3+1]=Pc[1]; P[j*3+2]=Pc[2];
        if (j==11) { for (int i=0;i<9;++i) R11[i]=R[i]; P11[0]=Pc[0];P11[1]=Pc[1];P11[2]=Pc[2]; }
        if (j==12) { for (int i=0;i<9;++i) R12[i]=R[i]; P12[0]=Pc[0];P12[1]=Pc[1];P12[2]=Pc[2]; }
    }
}

extern "C" void kernel_launch(void* const* d_in, const int* in_sizes, int n_in,
                              void* d_out, int out_size, void* d_ws, size_t ws_size,
                              hipStream_t stream) {
    const float* x   = (const float*)d_in[0];
    const float* off = (const float*)d_in[2];
    float* out = (float*)d_out;
    int B = in_sizes[0] / 144;
    int nb = B / GPB;
    if (nb > 0)
        fk_kernel<<<nb, GPB, 0, stream>>>(x, off, out, B);
    int rem = B - nb * GPB;
    if (rem > 0)
        fk_tail<<<(rem + 255) / 256, 256, 0, stream>>>(x, off, out, nb * GPB, B);
}